// Round 12
// baseline (123.162 us; speedup 1.0000x reference)
//
#include <hip/hip_runtime.h>
#include <hip/hip_bf16.h>

typedef __attribute__((ext_vector_type(8))) short short8;   // 8 x bf16
typedef __attribute__((ext_vector_type(4))) float f32x4;

#define MFMA16(a, b, c) __builtin_amdgcn_mfma_f32_16x16x32_bf16((a), (b), (c), 0, 0, 0)
#define QSCALE 0.18033688f    /* 0.125 * log2(e): fold score scale into Q */
#define EXP2F(x) __builtin_amdgcn_exp2f(x)

__device__ __forceinline__ unsigned short f2bf(float f) {       // RNE
    unsigned u = __builtin_bit_cast(unsigned, f);
    u += 0x7FFFu + ((u >> 16) & 1u);
    return (unsigned short)(u >> 16);
}
__device__ __forceinline__ unsigned short bfc(float f) {        // cheap round
    return (unsigned short)((__builtin_bit_cast(unsigned, f) + 0x8000u) >> 16);
}

__device__ __forceinline__ short8 pack8(float4 a, float4 b) {
    short8 r;
    r[0] = (short)f2bf(a.x); r[1] = (short)f2bf(a.y);
    r[2] = (short)f2bf(a.z); r[3] = (short)f2bf(a.w);
    r[4] = (short)f2bf(b.x); r[5] = (short)f2bf(b.y);
    r[6] = (short)f2bf(b.z); r[7] = (short)f2bf(b.w);
    return r;
}
__device__ __forceinline__ short8 pack8s(float4 a, float4 b, float s) {
    short8 r;
    r[0] = (short)f2bf(a.x * s); r[1] = (short)f2bf(a.y * s);
    r[2] = (short)f2bf(a.z * s); r[3] = (short)f2bf(a.w * s);
    r[4] = (short)f2bf(b.x * s); r[5] = (short)f2bf(b.y * s);
    r[6] = (short)f2bf(b.z * s); r[7] = (short)f2bf(b.w * s);
    return r;
}

__device__ __forceinline__ void stage16(const void* g, void* l) {
    __builtin_amdgcn_global_load_lds((const __attribute__((address_space(1))) void*)g,
                                     (__attribute__((address_space(3))) void*)l, 16, 0, 0);
}
__device__ __forceinline__ float bpermf(int sa, float v) {
    return __builtin_bit_cast(float,
        __builtin_amdgcn_ds_bpermute(sa, __builtin_bit_cast(int, v)));
}

// ---------------- merged pre-kernel ----------------
// blocks [0,6144): K f32 -> Kws bf16, elem e stored from e^((j&7)<<3) (pre-swizzle)
// blocks [6144,9216): V -> Vws2 [b][h(64)][j(1536)] bf16 plain transpose
// blocks [9216,9472): key_pe [64][1024] f32 -> PET [1024][64] bf16
__global__ void conv_all_kernel(const float* __restrict__ K, const float* __restrict__ V,
                                const float* __restrict__ PE,
                                unsigned short* __restrict__ Kws,
                                unsigned short* __restrict__ Vws2,
                                unsigned short* __restrict__ PET) {
    __shared__ unsigned short T[64][72];
    const int blk = blockIdx.x, tid = threadIdx.x;
    if (blk < 6144) {
        int idx = blk * 256 + tid;                // 1,572,864
        int jl = idx >> 3;                        // b*1536 + j
        int e0 = (idx & 7) << 3;
        int x  = (jl & 7) << 3;
        const float* src = K + ((size_t)jl << 6) + (e0 ^ x);
        float4 a = ((const float4*)src)[0], b = ((const float4*)src)[1];
        *(short8*)(Kws + ((size_t)jl << 6) + e0) = pack8(a, b);
    } else if (blk < 9216) {
        int blkv = blk - 6144;                    // 128 b x 24 blk64
        int b = blkv / 24, vb = blkv - b * 24;
        {
            int j = tid >> 2, h0 = (tid & 3) << 4;
            const float* src = V + ((size_t)(b * 1536 + vb * 64 + j) << 6) + h0;
            float4 a0 = ((const float4*)src)[0], a1 = ((const float4*)src)[1];
            float4 a2 = ((const float4*)src)[2], a3 = ((const float4*)src)[3];
            *(short8*)&T[j][h0]     = pack8(a0, a1);
            *(short8*)&T[j][h0 + 8] = pack8(a2, a3);
        }
        __syncthreads();
        {
            int h = tid >> 2, k0 = (tid & 3) << 4;      // consecutive tid -> contiguous 32B
            unsigned short* dst = Vws2 + ((size_t)(b * 64 + h)) * 1536 + vb * 64 + k0;
            short8 o0, o1;
#pragma unroll
            for (int u = 0; u < 8; ++u) o0[u] = (short)T[k0 + u][h];
#pragma unroll
            for (int u = 0; u < 8; ++u) o1[u] = (short)T[k0 + 8 + u][h];
            ((short8*)dst)[0] = o0;
            ((short8*)dst)[1] = o1;
        }
    } else {
        int idx = (blk - 9216) * 256 + tid;       // 65536
        int l = idx >> 6, h = idx & 63;
        PET[idx] = f2bf(PE[(h << 10) | l]);
    }
}

// PE-only transpose (fallback path)
__global__ void pe_only_kernel(const float* __restrict__ pe,
                               unsigned short* __restrict__ pet) {
    int idx = blockIdx.x * 256 + threadIdx.x;
    int l = idx >> 6, h = idx & 63;
    pet[idx] = f2bf(pe[(h << 10) | l]);
}

// ---------------- main kernel (v11): 1-wave blocks, barrier-free ----------------
// 4096 blocks x 64 threads. Each wave owns 16 q-rows (b, u); 32-key tiles,
// double-buffered 16KB LDS, wave-private (NO s_barrier anywhere). Tile t covers
// l = 32t + 16jc + (c16-ii); tiles t in [t0, 32]; edge (l-range clamp) only at
// t==0 and t==32. Adaptive-span skip: tile fully masked iff 32t+31 <= 991-1024z.
__global__ __launch_bounds__(64, 4) void attn_v11(
    const float* __restrict__ Qg, const unsigned short* __restrict__ Kws,
    const unsigned short* __restrict__ Vws2, const unsigned short* __restrict__ PET,
    const float* __restrict__ SPAN, float* __restrict__ OUT)
{
    __shared__ unsigned short Klds[2][2048];   // 2 x 4KB [k32][e64]; W (1KB) aliases
    __shared__ unsigned short Vlds[2][2048];   // 2 x 4KB [h64][kk32], xh-swizzled

    const int bid = blockIdx.x;
    const int x = bid & 7, y = (bid >> 3) & 15, u = bid >> 7;  // 8 x 16 x 32
    const int b = x * 16 + y;                  // same-b blocks share an XCD
    const int lane = threadIdx.x;
    const int c16 = lane & 15, g = lane >> 4;

    float z = SPAN[b & 15];
    z = fminf(fmaxf(z, 0.f), 1.f);
    const float mc = z * 32.f + 1.f - 1023.f * 0.03125f;   // msk = clamp(l/32 + mc, 0, 1)
    int t0 = (int)floorf(29.99f - 32.f * z) + 1;           // tiles < t0 fully masked
    if (t0 < 0) t0 = 0;

    short8 qf0, qf1;      // Q pre-scaled by 0.125*log2e
    {
        const float* qp = Qg + ((size_t)((b << 9) + (u << 4) + c16) << 6) + (g << 3);
        qf0 = pack8s(*(const float4*)qp,        *(const float4*)(qp + 4),  QSCALE);
        qf1 = pack8s(*(const float4*)(qp + 32), *(const float4*)(qp + 36), QSCALE);
    }

    const f32x4 zero = {0.f, 0.f, 0.f, 0.f};
    f32x4 Oacc[4] = {zero, zero, zero, zero};
    f32x4 sumw = zero, sume = zero;
    f32x4 Sp[3];

    // K: rows j = 16u + 32t + klocal of Kws[b] (row = 128B, pre-swizzled per row)
    const char* kbase = (const char*)Kws + (((size_t)b * 1536 + (u << 4)) << 7);
    // V: Vws2[b][h][j]; LDS [h][kk32] with kk ^ ((h&3)<<3) source swizzle
    const unsigned short* vb0 = Vws2 + (size_t)b * 98304;   // 64*1536
    int voff[4];
#pragma unroll
    for (int c = 0; c < 4; ++c) {
        int o  = c * 1024 + lane * 16;          // byte offset in 4KB tile
        int h  = o >> 6;
        int kk = (o & 63) >> 1;
        voff[c] = h * 1536 + (kk ^ ((h & 3) << 3));
    }
    // bpermute source addresses (loop-invariant per r)
    int bsrc[4];
#pragma unroll
    for (int r = 0; r < 4; ++r)
        bsrc[r] = ((lane & 48) | ((c16 - (g << 2) - r) & 15)) << 2;

#define STAGE(bufi, t) do {                                                    \
        const char* kg_ = kbase + (t) * 4096 + lane * 16;                      \
        const int  js_ = (u << 4) + ((t) << 5);                                \
        _Pragma("unroll")                                                      \
        for (int c_ = 0; c_ < 4; ++c_) {                                       \
            stage16(kg_ + c_ * 1024, (char*)Klds[bufi] + c_ * 1024);           \
            stage16((const char*)(vb0 + voff[c_] + js_),                       \
                    (char*)Vlds[bufi] + c_ * 1024);                            \
        }                                                                      \
    } while (0)

#define STRIP(dst, lbase) do {                                                 \
        int lr_ = (lbase) + c16;                                               \
        lr_ = lr_ < 0 ? 0 : (lr_ > 1023 ? 1023 : lr_);                         \
        const unsigned short* pp_ = PET + ((lr_ << 6) + (g << 3));             \
        short8 p0_ = *(const short8*)pp_;                                      \
        short8 p1_ = *(const short8*)(pp_ + 32);                               \
        f32x4 a_ = MFMA16(qf0, p0_, zero);                                     \
        dst = MFMA16(qf1, p1_, a_);                                            \
    } while (0)

    STAGE(t0 & 1, t0);
    STRIP(Sp[2], (t0 << 5) - 16);              // becomes Sp[0] at t=t0

    for (int t = t0; t <= 32; ++t) {
        const int buf = t & 1;
        // tile t landed (stage issued one full iteration ago)
        asm volatile("s_waitcnt vmcnt(0)" ::: "memory");
        __builtin_amdgcn_sched_barrier(0);
        // prior iteration's PV/W ds ops retired -> safe to re-stage buf^1
        asm volatile("s_waitcnt lgkmcnt(0)" ::: "memory");
        __builtin_amdgcn_sched_barrier(0);
        if (t < 32) STAGE(buf ^ 1, t + 1);

        const int d0 = t << 5;
        const bool edge = (t == 0) || (t == 32);

        __builtin_amdgcn_s_setprio(1);
        // ---- content scores from Klds[buf] (32 keys) ----
        f32x4 Sc[2];
        const int xk = (c16 & 7) << 3;
#pragma unroll
        for (int jc = 0; jc < 2; ++jc) {
            const unsigned short* p = &Klds[buf][(jc * 16 + c16) << 6];
            short8 k0 = *(const short8*)(p + ((g << 3) ^ xk));
            short8 k1 = *(const short8*)(p + (((g << 3) + 32) ^ xk));
            f32x4 a = MFMA16(qf0, k0, zero);
            Sc[jc] = MFMA16(qf1, k1, a);
        }
        // ---- positional strips (3-strip rolling window) ----
        Sp[0] = Sp[2];
        STRIP(Sp[1], d0);
        STRIP(Sp[2], d0 + 16);
        __builtin_amdgcn_s_setprio(0);

        // ---- combine + exp + span mask -> W (bf16, in Klds[buf], wave-local) ----
        unsigned short* Wp = &Klds[buf][0];    // 16x32 bf16 = 1KB
#pragma unroll
        for (int r = 0; r < 4; ++r) {
            const int ii    = (g << 2) + r;
            const int delta = c16 - ii;
            const int sa    = bsrc[r];
            float sh0 = bpermf(sa, Sp[0][r]);
            float sh1 = bpermf(sa, Sp[1][r]);
            float sh2 = bpermf(sa, Sp[2][r]);
            const bool lo_ = delta < 0;
            const int xw = (ii & 3) << 3;
            const int lbase = d0 + delta;
            const float mb = fmaf((float)lbase, 0.03125f, mc);
#pragma unroll
            for (int jc = 0; jc < 2; ++jc) {
                const float pa = (jc == 0) ? sh0 : sh1;
                const float pb = (jc == 0) ? sh1 : sh2;
                const float pe = lo_ ? pa : pb;
                float e = EXP2F(Sc[jc][r] + pe);
                if (edge) {                    // wave-uniform branch
                    const int l_ = lbase + (jc << 4);
                    if ((unsigned)l_ >= 1024u) e = 0.f;
                }
                const float m_ = fminf(fmaxf(mb + 0.5f * jc, 0.f), 1.f);
                const float wgt = e * m_;
                sumw[r] += wgt;
                sume[r] += e;
                Wp[(ii << 5) + (((jc << 4) + c16) ^ xw)] = bfc(wgt);
            }
        }

        // ---- PV: one A-frag (k=32), 4 B-tiles from Vlds[buf] ----
        const int xr = (c16 & 3) << 3;
        short8 wf = *(const short8*)(Wp + (c16 << 5) + ((g << 3) ^ xr));
        __builtin_amdgcn_s_setprio(1);
#pragma unroll
        for (int ht = 0; ht < 4; ++ht) {
            const int h = ht * 16 + c16;
            const unsigned short* vr = &Vlds[buf][(h << 5) + ((g << 3) ^ ((h & 3) << 3))];
            short8 v0 = *(const short8*)vr;
            Oacc[ht] = MFMA16(wf, v0, Oacc[ht]);
        }
        __builtin_amdgcn_s_setprio(0);
    }

    // ---- epilogue ----
#pragma unroll
    for (int r = 0; r < 4; ++r) {
        float sw = sumw[r], se = sume[r];
#pragma unroll
        for (int m = 1; m < 16; m <<= 1) {
            sw += __shfl_xor(sw, m, 64);
            se += __shfl_xor(se, m, 64);
        }
        const float inv = 1.0f / (sw + 1e-8f * se);
        float* op = OUT + ((size_t)((b << 9) + (u << 4) + (g << 2) + r) << 6);
#pragma unroll
        for (int ht = 0; ht < 4; ++ht)
            op[ht * 16 + c16] = Oacc[ht][r] * inv;
    }
#undef STAGE
#undef STRIP
}

// ---------------- fallback v1 (ws too small for conversions) ----------------
__global__ __launch_bounds__(256, 4) void attn_v1(
    const float* __restrict__ Qg, const float* __restrict__ Kg,
    const float* __restrict__ Vg, const unsigned short* __restrict__ PET,
    const float* __restrict__ SPAN, float* __restrict__ OUT)
{
    __shared__ unsigned short Klds[64 * 72];
    __shared__ unsigned short Vlds[64 * 72];
    __shared__ unsigned short Wlds[4][16 * 72];

    const int bid = blockIdx.x;
    const int b  = (bid & 7) * 16 + (bid >> 6);
    const int qt = (bid >> 3) & 7;
    const int i0 = qt << 6;
    const int tid = threadIdx.x, w = tid >> 6, lane = tid & 63;
    const int c16 = lane & 15, g = lane >> 4;

    float z = SPAN[b & 15];
    z = fminf(fmaxf(z, 0.0f), 1.0f);
    const float zc = z * 32.0f + 1.0f;

    short8 qf0, qf1;
    {
        const float* qp = Qg + ((size_t)(b * 512 + i0 + w * 16 + c16) * 64 + g * 8);
        qf0 = pack8(*(const float4*)qp,        *(const float4*)(qp + 4));
        qf1 = pack8(*(const float4*)(qp + 32), *(const float4*)(qp + 36));
    }
    const f32x4 zero = {0.f, 0.f, 0.f, 0.f};
    f32x4 Oacc[4] = {zero, zero, zero, zero};
    f32x4 sumw = zero, sume = zero;
    const int d0w_off = -(w << 4);

    for (int dblk = 0; dblk < 17; ++dblk) {
        const int d = dblk << 6;
        __syncthreads();
        {
            const int row = tid >> 2, h0 = (tid & 3) << 4;
            const float* kp = Kg + ((size_t)(b * 1536 + i0 + d + row) * 64 + h0);
            float4 k0 = ((const float4*)kp)[0], k1 = ((const float4*)kp)[1];
            float4 k2 = ((const float4*)kp)[2], k3 = ((const float4*)kp)[3];
            *(short8*)&Klds[row * 72 + h0]     = pack8(k0, k1);
            *(short8*)&Klds[row * 72 + h0 + 8] = pack8(k2, k3);
        }
        {
            const int j0 = (tid & 31) << 1, h0 = (tid >> 5) << 3;
            const float* vp = Vg + ((size_t)(b * 1536 + i0 + d + j0) * 64 + h0);
            float4 a0 = ((const float4*)vp)[0], a1 = ((const float4*)vp)[1];
            float4 b0 = ((const float4*)(vp + 64))[0], b1 = ((const float4*)(vp + 64))[1];
            float ta[8] = {a0.x, a0.y, a0.z, a0.w, a1.x, a1.y, a1.z, a1.w};
            float tb[8] = {b0.x, b0.y, b0.z, b0.w, b1.x, b1.y, b1.z, b1.w};
#pragma unroll
            for (int uu = 0; uu < 8; ++uu) {
                unsigned pv = (unsigned)f2bf(ta[uu]) | ((unsigned)f2bf(tb[uu]) << 16);
                *(unsigned*)&Vlds[(h0 + uu) * 72 + j0] = pv;
            }
        }
        __syncthreads();

        const int d0w = d + d0w_off;
        const int lb  = d0w - 16;
        f32x4 Sp[5];
#pragma unroll
        for (int tt = 0; tt < 5; ++tt) {
            int lr = lb + (tt << 4) + c16;
            lr = lr < 0 ? 0 : (lr > 1023 ? 1023 : lr);
            const unsigned short* pp = PET + ((lr << 6) + (g << 3));
            short8 p0 = *(const short8*)pp;
            short8 p1 = *(const short8*)(pp + 32);
            f32x4 acc = MFMA16(qf0, p0, zero);
            Sp[tt] = MFMA16(qf1, p1, acc);
        }
        f32x4 Sc[4];
#pragma unroll
        for (int jc = 0; jc < 4; ++jc) {
            const unsigned short* kb = &Klds[(jc * 16 + c16) * 72 + (g << 3)];
            short8 k0 = *(const short8*)kb;
            short8 k1 = *(const short8*)(kb + 32);
            f32x4 acc = MFMA16(qf0, k0, zero);
            Sc[jc] = MFMA16(qf1, k1, acc);
        }
        unsigned short* Wp = Wlds[w];
#pragma unroll
        for (int jc = 0; jc < 4; ++jc) {
#pragma unroll
            for (int r = 0; r < 4; ++r) {
                const int ii    = (g << 2) + r;
                const int delta = c16 - ii;
                const int src   = (lane & 48) | (delta & 15);
                const float pa  = __shfl(Sp[jc][r],     src, 64);
                const float pb  = __shfl(Sp[jc + 1][r], src, 64);
                const float pe  = (delta >= 0) ? pb : pa;
                const int l     = d0w + (jc << 4) + delta;
                const float sv  = (Sc[jc][r] + pe) * 0.125f;
                const float e   = __expf(sv);
                const bool valid = ((unsigned)l < 1024u);
                float msk = (float)(l - 1023) * 0.03125f + zc;
                msk = fminf(fmaxf(msk, 0.0f), 1.0f);
                const float wgt = valid ? e * msk : 0.0f;
                sumw[r] += wgt;
                sume[r] += valid ? e : 0.0f;
                Wp[ii * 72 + (jc << 4) + c16] = f2bf(wgt);
            }
        }
        short8 wf0 = *(const short8*)&Wp[c16 * 72 + (g << 3)];
        short8 wf1 = *(const short8*)&Wp[c16 * 72 + 32 + (g << 3)];
#pragma unroll
        for (int ht = 0; ht < 4; ++ht) {
            const unsigned short* vb = &Vlds[(ht * 16 + c16) * 72 + (g << 3)];
            short8 v0 = *(const short8*)vb;
            short8 v1 = *(const short8*)(vb + 32);
            f32x4 a = MFMA16(wf0, v0, Oacc[ht]);
            Oacc[ht] = MFMA16(wf1, v1, a);
        }
    }
#pragma unroll
    for (int r = 0; r < 4; ++r) {
        float sw = sumw[r], se = sume[r];
#pragma unroll
        for (int m = 1; m < 16; m <<= 1) {
            sw += __shfl_xor(sw, m, 64);
            se += __shfl_xor(se, m, 64);
        }
        const float inv = 1.0f / (sw + 1e-8f * se);
        float* op = OUT + ((size_t)(b * 512 + i0 + w * 16 + (g << 2) + r) * 64);
#pragma unroll
        for (int ht = 0; ht < 4; ++ht)
            op[ht * 16 + c16] = Oacc[ht][r] * inv;
    }
}

extern "C" void kernel_launch(void* const* d_in, const int* in_sizes, int n_in,
                              void* d_out, int out_size, void* d_ws, size_t ws_size,
                              hipStream_t stream) {
    const float* Q    = (const float*)d_in[0];
    const float* K    = (const float*)d_in[1];
    const float* V    = (const float*)d_in[2];
    const float* PE   = (const float*)d_in[3];
    const float* SPAN = (const float*)d_in[4];

    const size_t VWS  = (size_t)128 * 64 * 1536 * 2;     // 25,165,824 (Vws2)
    const size_t KWS  = (size_t)128 * 1536 * 64 * 2;     // 25,165,824
    const size_t PETB = (size_t)1024 * 64 * 2;           // 131,072
    const size_t NEED = VWS + KWS + PETB;

    if (ws_size >= NEED) {
        unsigned short* Vws2 = (unsigned short*)d_ws;
        unsigned short* Kws  = (unsigned short*)((char*)d_ws + VWS);
        unsigned short* PET  = (unsigned short*)((char*)d_ws + VWS + KWS);
        conv_all_kernel<<<9472, 256, 0, stream>>>(K, V, PE, Kws, Vws2, PET);
        attn_v11<<<4096, 64, 0, stream>>>(Q, Kws, Vws2, PET, SPAN, (float*)d_out);
    } else {
        unsigned short* PET = (unsigned short*)d_ws;
        pe_only_kernel<<<256, 256, 0, stream>>>(PE, PET);
        attn_v1<<<1024, 256, 0, stream>>>(Q, K, V, PET, SPAN, (float*)d_out);
    }
}

// Round 13
// 94.650 us; speedup vs baseline: 1.3012x; 1.3012x over previous
//
#include <hip/hip_runtime.h>
#include <hip/hip_bf16.h>

typedef __attribute__((ext_vector_type(8))) short short8;   // 8 x bf16
typedef __attribute__((ext_vector_type(4))) float f32x4;

#define MFMA16(a, b, c) __builtin_amdgcn_mfma_f32_16x16x32_bf16((a), (b), (c), 0, 0, 0)
#define QSCALE 0.18033688f    /* 0.125 * log2(e): fold score scale into Q */
#define EXP2F(x) __builtin_amdgcn_exp2f(x)

__device__ __forceinline__ unsigned short f2bf(float f) {       // RNE
    unsigned u = __builtin_bit_cast(unsigned, f);
    u += 0x7FFFu + ((u >> 16) & 1u);
    return (unsigned short)(u >> 16);
}
__device__ __forceinline__ unsigned short bfc(float f) {        // cheap round
    return (unsigned short)((__builtin_bit_cast(unsigned, f) + 0x8000u) >> 16);
}

__device__ __forceinline__ short8 pack8(float4 a, float4 b) {
    short8 r;
    r[0] = (short)f2bf(a.x); r[1] = (short)f2bf(a.y);
    r[2] = (short)f2bf(a.z); r[3] = (short)f2bf(a.w);
    r[4] = (short)f2bf(b.x); r[5] = (short)f2bf(b.y);
    r[6] = (short)f2bf(b.z); r[7] = (short)f2bf(b.w);
    return r;
}
__device__ __forceinline__ short8 pack8s(float4 a, float4 b, float s) {
    short8 r;
    r[0] = (short)f2bf(a.x * s); r[1] = (short)f2bf(a.y * s);
    r[2] = (short)f2bf(a.z * s); r[3] = (short)f2bf(a.w * s);
    r[4] = (short)f2bf(b.x * s); r[5] = (short)f2bf(b.y * s);
    r[6] = (short)f2bf(b.z * s); r[7] = (short)f2bf(b.w * s);
    return r;
}

__device__ __forceinline__ void stage16(const void* g, void* l) {
    __builtin_amdgcn_global_load_lds((const __attribute__((address_space(1))) void*)g,
                                     (__attribute__((address_space(3))) void*)l, 16, 0, 0);
}
__device__ __forceinline__ float bpermf(int sa, float v) {
    return __builtin_bit_cast(float,
        __builtin_amdgcn_ds_bpermute(sa, __builtin_bit_cast(int, v)));
}

// ---------------- merged pre-kernel ----------------
// blocks [0,6144): K f32 -> Kws bf16, elem e stored from e^((j&7)<<3) (pre-swizzle)
// blocks [6144,9216): V -> Vws [b][blk(24)][h(64)][kk(64)] bf16 transposed, pre-swizzled
// blocks [9216,9472): key_pe [64][1024] f32 -> PET [1024][64] bf16
__global__ void conv_all_kernel(const float* __restrict__ K, const float* __restrict__ V,
                                const float* __restrict__ PE,
                                unsigned short* __restrict__ Kws,
                                unsigned short* __restrict__ Vws,
                                unsigned short* __restrict__ PET) {
    __shared__ unsigned short T[64][72];
    const int blk = blockIdx.x, tid = threadIdx.x;
    if (blk < 6144) {
        int idx = blk * 256 + tid;                // 1,572,864
        int jl = idx >> 3;                        // b*1536 + j
        int e0 = (idx & 7) << 3;
        int x  = (jl & 7) << 3;
        const float* src = K + ((size_t)jl << 6) + (e0 ^ x);
        float4 a = ((const float4*)src)[0], b = ((const float4*)src)[1];
        *(short8*)(Kws + ((size_t)jl << 6) + e0) = pack8(a, b);
    } else if (blk < 9216) {
        int blkv = blk - 6144;
        int b = blkv / 24, vb = blkv - b * 24;
        {
            int j = tid >> 2, h0 = (tid & 3) << 4;
            const float* src = V + ((size_t)(b * 1536 + vb * 64 + j) << 6) + h0;
            float4 a0 = ((const float4*)src)[0], a1 = ((const float4*)src)[1];
            float4 a2 = ((const float4*)src)[2], a3 = ((const float4*)src)[3];
            *(short8*)&T[j][h0]     = pack8(a0, a1);
            *(short8*)&T[j][h0 + 8] = pack8(a2, a3);
        }
        __syncthreads();
        {
            int h = tid & 63, k0 = (tid >> 6) << 4;
            int x = (h & 7) << 3;
            unsigned short* dst = Vws + ((size_t)(b * 24 + vb) << 12) + (h << 6) + k0;
            short8 o0, o1;
#pragma unroll
            for (int u = 0; u < 8; ++u) o0[u] = (short)T[(k0 + u) ^ x][h];
#pragma unroll
            for (int u = 0; u < 8; ++u) o1[u] = (short)T[(k0 + 8 + u) ^ x][h];
            ((short8*)dst)[0] = o0;
            ((short8*)dst)[1] = o1;
        }
    } else {
        int idx = (blk - 9216) * 256 + tid;       // 65536
        int l = idx >> 6, h = idx & 63;
        PET[idx] = f2bf(PE[(h << 10) | l]);
    }
}

// PE-only transpose (fallback path)
__global__ void pe_only_kernel(const float* __restrict__ pe,
                               unsigned short* __restrict__ pet) {
    int idx = blockIdx.x * 256 + threadIdx.x;
    int l = idx >> 6, h = idx & 63;
    pet[idx] = f2bf(pe[(h << 10) | l]);
}

// ---------------- main kernel (v12): v10 + hoisted strip loads, no setprio ----------------
__global__ __launch_bounds__(256, 4) void attn_v12(
    const float* __restrict__ Qg, const unsigned short* __restrict__ Kws,
    const unsigned short* __restrict__ Vws, const unsigned short* __restrict__ PET,
    const float* __restrict__ SPAN, float* __restrict__ OUT)
{
    __shared__ unsigned short Klds[2][4096];      // 16 KB; dead half doubles as W
    __shared__ unsigned short Vlds[2][4096];      // 16 KB

    const int bid = blockIdx.x;
    const int b   = (bid & 7) * 16 + (bid >> 6);  // XCD swizzle (proven decode)
    const int i0  = ((bid >> 3) & 7) << 6;
    const int tid = threadIdx.x, w = tid >> 6, lane = tid & 63;
    const int c16 = lane & 15, g = lane >> 4;

    float z = SPAN[b & 15];
    z = fminf(fmaxf(z, 0.f), 1.f);
    const float mc = z * 32.f + 1.f - 1023.f * 0.03125f;   // msk = clamp(l/32 + mc, 0, 1)

    // adaptive-span tile skip: tiles t < t_start are fully masked for this head
    int t_start = (int)floorf(14.46f - 16.f * z) + 1;
    if (t_start < 0) t_start = 0;

    short8 qf0, qf1;      // Q pre-scaled by 0.125*log2e
    {
        const float* qp = Qg + ((size_t)((b << 9) + i0 + (w << 4) + c16) << 6) + (g << 3);
        qf0 = pack8s(*(const float4*)qp,        *(const float4*)(qp + 4),  QSCALE);
        qf1 = pack8s(*(const float4*)(qp + 32), *(const float4*)(qp + 36), QSCALE);
    }

    const f32x4 zero = {0.f, 0.f, 0.f, 0.f};
    f32x4 Oacc[4] = {zero, zero, zero, zero};
    f32x4 sumw = zero, sume = zero;
    f32x4 Sp[5];

    const char* kbase = (const char*)Kws + (((size_t)b * 1536 + i0) << 7);
    const char* vbase = (const char*)Vws + (((size_t)b * 24 + (i0 >> 6)) << 13);
    const int ubase = w << 10;                     // wave-uniform byte off in 8KB block
    const int loff  = ubase + lane * 16;

    // bpermute source addresses (loop-invariant per r)
    int bsrc[4];
#pragma unroll
    for (int r = 0; r < 4; ++r)
        bsrc[r] = ((lane & 48) | ((c16 - (g << 2) - r) & 15)) << 2;

#define STAGE(bufi, t) do {                                                    \
        const char* kg_ = kbase + (t) * 8192 + loff;                           \
        const char* vg_ = vbase + (t) * 8192 + loff;                           \
        unsigned short* kl_ = &Klds[bufi][ubase >> 1];                         \
        unsigned short* vl_ = &Vlds[bufi][ubase >> 1];                         \
        stage16(kg_, kl_); stage16(kg_ + 4096, kl_ + 2048);                    \
        stage16(vg_, vl_); stage16(vg_ + 4096, vl_ + 2048);                    \
    } while (0)

#define STRIP(dst, lbase) do {                                                 \
        int lr_ = (lbase) + c16;                                               \
        lr_ = lr_ < 0 ? 0 : (lr_ > 1023 ? 1023 : lr_);                         \
        const unsigned short* pp_ = PET + ((lr_ << 6) + (g << 3));             \
        short8 p0_ = *(const short8*)pp_;                                      \
        short8 p1_ = *(const short8*)(pp_ + 32);                               \
        f32x4 a_ = MFMA16(qf0, p0_, zero);                                     \
        dst = MFMA16(qf1, p1_, a_);                                            \
    } while (0)

    STAGE(t_start & 1, t_start);
    { const int lb0 = (t_start << 6) - (w << 4) - 16; STRIP(Sp[4], lb0); }

    for (int t = t_start; t < 17; ++t) {
        const int buf = t & 1;
        __syncthreads();                           // barrier1: stage(t) drained
        if (t < 16) STAGE(buf ^ 1, t + 1);         // prefetch; in flight past barrier2

        const int d0w = (t << 6) - (w << 4);
        const bool edge = (t == 0) || (t == 16);

        // ---- hoisted strip operand loads (latency hides under Sc) ----
        short8 sp0[4], sp1[4];
#pragma unroll
        for (int s = 0; s < 4; ++s) {
            int lr = d0w + (s << 4) + c16;
            lr = lr < 0 ? 0 : (lr > 1023 ? 1023 : lr);
            const unsigned short* pp = PET + ((lr << 6) + (g << 3));
            sp0[s] = *(const short8*)pp;
            sp1[s] = *(const short8*)(pp + 32);
        }

        // ---- content scores from Klds[buf] ----
        f32x4 Sc[4];
        const int xk = (c16 & 7) << 3;
#pragma unroll
        for (int jc = 0; jc < 4; ++jc) {
            const unsigned short* p = &Klds[buf][(jc * 16 + c16) << 6];
            short8 k0 = *(const short8*)(p + ((g << 3) ^ xk));
            short8 k1 = *(const short8*)(p + (((g << 3) + 32) ^ xk));
            f32x4 a = MFMA16(qf0, k0, zero);
            Sc[jc] = MFMA16(qf1, k1, a);
        }
        // ---- positional strips from preloaded operands (rolling reuse) ----
        Sp[0] = Sp[4];
#pragma unroll
        for (int s = 0; s < 4; ++s) {
            f32x4 a = MFMA16(qf0, sp0[s], zero);
            Sp[s + 1] = MFMA16(qf1, sp1[s], a);
        }

        // barrier2: all waves' Klds[buf] reads COMPLETE before W aliases it.
        asm volatile("s_waitcnt lgkmcnt(0)" ::: "memory");
        __builtin_amdgcn_sched_barrier(0);
        __builtin_amdgcn_s_barrier();
        __builtin_amdgcn_sched_barrier(0);

        // ---- combine + exp + span mask -> W (bf16, swizzled, in Klds[buf]) ----
        unsigned short* Wp = &Klds[buf][w << 10];  // per-wave 2KB slice
#pragma unroll
        for (int r = 0; r < 4; ++r) {
            const int ii    = (g << 2) + r;
            const int delta = c16 - ii;
            const int sa    = bsrc[r];
            float sh0 = bpermf(sa, Sp[0][r]);
            float sh1 = bpermf(sa, Sp[1][r]);
            float sh2 = bpermf(sa, Sp[2][r]);
            float sh3 = bpermf(sa, Sp[3][r]);
            float sh4 = bpermf(sa, Sp[4][r]);
            const bool lo_ = delta < 0;
            const int xw = (ii & 7) << 3;
            const int lbase = d0w + delta;
            const float mb = fmaf((float)lbase, 0.03125f, mc);
#pragma unroll
            for (int jc = 0; jc < 4; ++jc) {
                float pa, pb;
                if (jc == 0) { pa = sh0; pb = sh1; }
                else if (jc == 1) { pa = sh1; pb = sh2; }
                else if (jc == 2) { pa = sh2; pb = sh3; }
                else { pa = sh3; pb = sh4; }
                const float pe = lo_ ? pa : pb;
                float e = EXP2F(Sc[jc][r] + pe);
                if (edge) {                        // wave-uniform branch
                    const int l_ = lbase + (jc << 4);
                    if ((unsigned)l_ >= 1024u) e = 0.f;
                }
                const float m_ = fminf(fmaxf(mb + 0.5f * jc, 0.f), 1.f);
                const float wgt = e * m_;
                sumw[r] += wgt;
                sume[r] += e;
                Wp[(ii << 6) + (((jc << 4) + c16) ^ xw)] = bfc(wgt);
            }
        }

        // ---- PV (W readback is wave-local; compiler orders lgkmcnt) ----
        const int xr = (c16 & 7) << 3;
        const unsigned short* wrow = Wp + (c16 << 6);
        short8 wf0 = *(const short8*)(wrow + ((g << 3) ^ xr));
        short8 wf1 = *(const short8*)(wrow + (((g << 3) + 32) ^ xr));
#pragma unroll
        for (int ht = 0; ht < 4; ++ht) {
            const unsigned short* vr = &Vlds[buf][(ht * 16 + c16) << 6];
            short8 v0 = *(const short8*)(vr + ((g << 3) ^ xr));
            short8 v1 = *(const short8*)(vr + (((g << 3) + 32) ^ xr));
            f32x4 a = MFMA16(wf0, v0, Oacc[ht]);
            Oacc[ht] = MFMA16(wf1, v1, a);
        }
    }

    // ---- epilogue ----
#pragma unroll
    for (int r = 0; r < 4; ++r) {
        float sw = sumw[r], se = sume[r];
#pragma unroll
        for (int m = 1; m < 16; m <<= 1) {
            sw += __shfl_xor(sw, m, 64);
            se += __shfl_xor(se, m, 64);
        }
        const float inv = 1.0f / (sw + 1e-8f * se);
        float* op = OUT + ((size_t)((b << 9) + i0 + (w << 4) + (g << 2) + r) << 6);
#pragma unroll
        for (int ht = 0; ht < 4; ++ht)
            op[ht * 16 + c16] = Oacc[ht][r] * inv;
    }
#undef STAGE
#undef STRIP
}

// ---------------- fallback v1 (ws too small for conversions) ----------------
__global__ __launch_bounds__(256, 4) void attn_v1(
    const float* __restrict__ Qg, const float* __restrict__ Kg,
    const float* __restrict__ Vg, const unsigned short* __restrict__ PET,
    const float* __restrict__ SPAN, float* __restrict__ OUT)
{
    __shared__ unsigned short Klds[64 * 72];
    __shared__ unsigned short Vlds[64 * 72];
    __shared__ unsigned short Wlds[4][16 * 72];

    const int bid = blockIdx.x;
    const int b  = (bid & 7) * 16 + (bid >> 6);
    const int qt = (bid >> 3) & 7;
    const int i0 = qt << 6;
    const int tid = threadIdx.x, w = tid >> 6, lane = tid & 63;
    const int c16 = lane & 15, g = lane >> 4;

    float z = SPAN[b & 15];
    z = fminf(fmaxf(z, 0.0f), 1.0f);
    const float zc = z * 32.0f + 1.0f;

    short8 qf0, qf1;
    {
        const float* qp = Qg + ((size_t)(b * 512 + i0 + w * 16 + c16) * 64 + g * 8);
        qf0 = pack8(*(const float4*)qp,        *(const float4*)(qp + 4));
        qf1 = pack8(*(const float4*)(qp + 32), *(const float4*)(qp + 36));
    }
    const f32x4 zero = {0.f, 0.f, 0.f, 0.f};
    f32x4 Oacc[4] = {zero, zero, zero, zero};
    f32x4 sumw = zero, sume = zero;
    const int d0w_off = -(w << 4);

    for (int dblk = 0; dblk < 17; ++dblk) {
        const int d = dblk << 6;
        __syncthreads();
        {
            const int row = tid >> 2, h0 = (tid & 3) << 4;
            const float* kp = Kg + ((size_t)(b * 1536 + i0 + d + row) * 64 + h0);
            float4 k0 = ((const float4*)kp)[0], k1 = ((const float4*)kp)[1];
            float4 k2 = ((const float4*)kp)[2], k3 = ((const float4*)kp)[3];
            *(short8*)&Klds[row * 72 + h0]     = pack8(k0, k1);
            *(short8*)&Klds[row * 72 + h0 + 8] = pack8(k2, k3);
        }
        {
            const int j0 = (tid & 31) << 1, h0 = (tid >> 5) << 3;
            const float* vp = Vg + ((size_t)(b * 1536 + i0 + d + j0) * 64 + h0);
            float4 a0 = ((const float4*)vp)[0], a1 = ((const float4*)vp)[1];
            float4 b0 = ((const float4*)(vp + 64))[0], b1 = ((const float4*)(vp + 64))[1];
            float ta[8] = {a0.x, a0.y, a0.z, a0.w, a1.x, a1.y, a1.z, a1.w};
            float tb[8] = {b0.x, b0.y, b0.z, b0.w, b1.x, b1.y, b1.z, b1.w};
#pragma unroll
            for (int u = 0; u < 8; ++u) {
                unsigned pv = (unsigned)f2bf(ta[u]) | ((unsigned)f2bf(tb[u]) << 16);
                *(unsigned*)&Vlds[(h0 + u) * 72 + j0] = pv;
            }
        }
        __syncthreads();

        const int d0w = d + d0w_off;
        const int lb  = d0w - 16;
        f32x4 Sp[5];
#pragma unroll
        for (int tt = 0; tt < 5; ++tt) {
            int lr = lb + (tt << 4) + c16;
            lr = lr < 0 ? 0 : (lr > 1023 ? 1023 : lr);
            const unsigned short* pp = PET + ((lr << 6) + (g << 3));
            short8 p0 = *(const short8*)pp;
            short8 p1 = *(const short8*)(pp + 32);
            f32x4 acc = MFMA16(qf0, p0, zero);
            Sp[tt] = MFMA16(qf1, p1, acc);
        }
        f32x4 Sc[4];
#pragma unroll
        for (int jc = 0; jc < 4; ++jc) {
            const unsigned short* kb = &Klds[(jc * 16 + c16) * 72 + (g << 3)];
            short8 k0 = *(const short8*)kb;
            short8 k1 = *(const short8*)(kb + 32);
            f32x4 acc = MFMA16(qf0, k0, zero);
            Sc[jc] = MFMA16(qf1, k1, acc);
        }
        unsigned short* Wp = Wlds[w];
#pragma unroll
        for (int jc = 0; jc < 4; ++jc) {
#pragma unroll
            for (int r = 0; r < 4; ++r) {
                const int ii    = (g << 2) + r;
                const int delta = c16 - ii;
                const int src   = (lane & 48) | (delta & 15);
                const float pa  = __shfl(Sp[jc][r],     src, 64);
                const float pb  = __shfl(Sp[jc + 1][r], src, 64);
                const float pe  = (delta >= 0) ? pb : pa;
                const int l     = d0w + (jc << 4) + delta;
                const float sv  = (Sc[jc][r] + pe) * 0.125f;
                const float e   = __expf(sv);
                const bool valid = ((unsigned)l < 1024u);
                float msk = (float)(l - 1023) * 0.03125f + zc;
                msk = fminf(fmaxf(msk, 0.0f), 1.0f);
                const float wgt = valid ? e * msk : 0.0f;
                sumw[r] += wgt;
                sume[r] += valid ? e : 0.0f;
                Wp[ii * 72 + (jc << 4) + c16] = f2bf(wgt);
            }
        }
        short8 wf0 = *(const short8*)&Wp[c16 * 72 + (g << 3)];
        short8 wf1 = *(const short8*)&Wp[c16 * 72 + 32 + (g << 3)];
#pragma unroll
        for (int ht = 0; ht < 4; ++ht) {
            const unsigned short* vb = &Vlds[(ht * 16 + c16) * 72 + (g << 3)];
            short8 v0 = *(const short8*)vb;
            short8 v1 = *(const short8*)(vb + 32);
            f32x4 a = MFMA16(wf0, v0, Oacc[ht]);
            Oacc[ht] = MFMA16(wf1, v1, a);
        }
    }
#pragma unroll
    for (int r = 0; r < 4; ++r) {
        float sw = sumw[r], se = sume[r];
#pragma unroll
        for (int m = 1; m < 16; m <<= 1) {
            sw += __shfl_xor(sw, m, 64);
            se += __shfl_xor(se, m, 64);
        }
        const float inv = 1.0f / (sw + 1e-8f * se);
        float* op = OUT + ((size_t)(b * 512 + i0 + w * 16 + (g << 2) + r) * 64);
#pragma unroll
        for (int ht = 0; ht < 4; ++ht)
            op[ht * 16 + c16] = Oacc[ht][r] * inv;
    }
}

extern "C" void kernel_launch(void* const* d_in, const int* in_sizes, int n_in,
                              void* d_out, int out_size, void* d_ws, size_t ws_size,
                              hipStream_t stream) {
    const float* Q    = (const float*)d_in[0];
    const float* K    = (const float*)d_in[1];
    const float* V    = (const float*)d_in[2];
    const float* PE   = (const float*)d_in[3];
    const float* SPAN = (const float*)d_in[4];

    const size_t VWS  = (size_t)128 * 24 * 4096 * 2;     // 25,165,824
    const size_t KWS  = (size_t)128 * 1536 * 64 * 2;     // 25,165,824
    const size_t PETB = (size_t)1024 * 64 * 2;           // 131,072
    const size_t NEED = VWS + KWS + PETB;

    if (ws_size >= NEED) {
        unsigned short* Vws = (unsigned short*)d_ws;
        unsigned short* Kws = (unsigned short*)((char*)d_ws + VWS);
        unsigned short* PET = (unsigned short*)((char*)d_ws + VWS + KWS);
        conv_all_kernel<<<9472, 256, 0, stream>>>(K, V, PE, Kws, Vws, PET);
        attn_v12<<<1024, 256, 0, stream>>>(Q, Kws, Vws, PET, SPAN, (float*)d_out);
    } else {
        unsigned short* PET = (unsigned short*)d_ws;
        pe_only_kernel<<<256, 256, 0, stream>>>(PE, PET);
        attn_v1<<<1024, 256, 0, stream>>>(Q, K, V, PET, SPAN, (float*)d_out);
    }
}

// Round 14
// 87.614 us; speedup vs baseline: 1.4057x; 1.0803x over previous
//
#include <hip/hip_runtime.h>
#include <hip/hip_bf16.h>

typedef __attribute__((ext_vector_type(8))) short short8;   // 8 x bf16
typedef __attribute__((ext_vector_type(4))) float f32x4;

#define MFMA16(a, b, c) __builtin_amdgcn_mfma_f32_16x16x32_bf16((a), (b), (c), 0, 0, 0)
#define QSCALE 0.18033688f    /* 0.125 * log2(e): fold score scale into Q */
#define EXP2F(x) __builtin_amdgcn_exp2f(x)

__device__ __forceinline__ int tstart_of(float z) {   // tiles < t_start fully masked
    int t = (int)floorf(14.46f - 16.f * z) + 1;
    return t < 0 ? 0 : t;
}

__device__ __forceinline__ unsigned short f2bf(float f) {       // RNE
    unsigned u = __builtin_bit_cast(unsigned, f);
    u += 0x7FFFu + ((u >> 16) & 1u);
    return (unsigned short)(u >> 16);
}
__device__ __forceinline__ unsigned short bfc(float f) {        // cheap round
    return (unsigned short)((__builtin_bit_cast(unsigned, f) + 0x8000u) >> 16);
}

__device__ __forceinline__ short8 pack8(float4 a, float4 b) {
    short8 r;
    r[0] = (short)f2bf(a.x); r[1] = (short)f2bf(a.y);
    r[2] = (short)f2bf(a.z); r[3] = (short)f2bf(a.w);
    r[4] = (short)f2bf(b.x); r[5] = (short)f2bf(b.y);
    r[6] = (short)f2bf(b.z); r[7] = (short)f2bf(b.w);
    return r;
}
__device__ __forceinline__ short8 pack8s(float4 a, float4 b, float s) {
    short8 r;
    r[0] = (short)f2bf(a.x * s); r[1] = (short)f2bf(a.y * s);
    r[2] = (short)f2bf(a.z * s); r[3] = (short)f2bf(a.w * s);
    r[4] = (short)f2bf(b.x * s); r[5] = (short)f2bf(b.y * s);
    r[6] = (short)f2bf(b.z * s); r[7] = (short)f2bf(b.w * s);
    return r;
}

__device__ __forceinline__ void stage16(const void* g, void* l) {
    __builtin_amdgcn_global_load_lds((const __attribute__((address_space(1))) void*)g,
                                     (__attribute__((address_space(3))) void*)l, 16, 0, 0);
}
__device__ __forceinline__ float bpermf(int sa, float v) {
    return __builtin_bit_cast(float,
        __builtin_amdgcn_ds_bpermute(sa, __builtin_bit_cast(int, v)));
}

// ---------------- merged pre-kernel (with adaptive-span conversion skip) ----------------
// blocks [0,6144): K f32 -> Kws bf16, elem e stored from e^((j&7)<<3) (pre-swizzle)
// blocks [6144,9216): V -> Vws [b][blk(24)][h(64)][kk(64)] bf16 transposed, pre-swizzled
// blocks [9216,9472): key_pe [64][1024] f32 -> PET [1024][64] bf16
// K/V rows j < 64*t_start(head) are never read by attn -> skip converting them.
__global__ void conv_all_kernel(const float* __restrict__ K, const float* __restrict__ V,
                                const float* __restrict__ PE,
                                const float* __restrict__ SPAN,
                                unsigned short* __restrict__ Kws,
                                unsigned short* __restrict__ Vws,
                                unsigned short* __restrict__ PET) {
    __shared__ unsigned short T[64][72];
    const int blk = blockIdx.x, tid = threadIdx.x;
    if (blk < 6144) {
        // 48 blocks per b (1536 rows / 32 rows per block), no b-straddle
        int b   = blk / 48;
        int j_hi = (blk - b * 48) * 32 + 31;
        float z = SPAN[b & 15];
        z = fminf(fmaxf(z, 0.f), 1.f);
        if (j_hi < (tstart_of(z) << 6)) return;    // entire block below first live row
        int idx = blk * 256 + tid;
        int jl = idx >> 3;                         // b*1536 + j
        int e0 = (idx & 7) << 3;
        int x  = (jl & 7) << 3;
        const float* src = K + ((size_t)jl << 6) + (e0 ^ x);
        float4 a = ((const float4*)src)[0], bb = ((const float4*)src)[1];
        *(short8*)(Kws + ((size_t)jl << 6) + e0) = pack8(a, bb);
    } else if (blk < 9216) {
        int blkv = blk - 6144;
        int b = blkv / 24, vb = blkv - b * 24;
        float z = SPAN[b & 15];
        z = fminf(fmaxf(z, 0.f), 1.f);
        if (vb * 64 + 63 < (tstart_of(z) << 6)) return;   // fully-skipped V rows
        {
            int j = tid >> 2, h0 = (tid & 3) << 4;
            const float* src = V + ((size_t)(b * 1536 + vb * 64 + j) << 6) + h0;
            float4 a0 = ((const float4*)src)[0], a1 = ((const float4*)src)[1];
            float4 a2 = ((const float4*)src)[2], a3 = ((const float4*)src)[3];
            *(short8*)&T[j][h0]     = pack8(a0, a1);
            *(short8*)&T[j][h0 + 8] = pack8(a2, a3);
        }
        __syncthreads();
        {
            int h = tid & 63, k0 = (tid >> 6) << 4;
            int x = (h & 7) << 3;
            unsigned short* dst = Vws + ((size_t)(b * 24 + vb) << 12) + (h << 6) + k0;
            short8 o0, o1;
#pragma unroll
            for (int u = 0; u < 8; ++u) o0[u] = (short)T[(k0 + u) ^ x][h];
#pragma unroll
            for (int u = 0; u < 8; ++u) o1[u] = (short)T[(k0 + 8 + u) ^ x][h];
            ((short8*)dst)[0] = o0;
            ((short8*)dst)[1] = o1;
        }
    } else {
        int idx = (blk - 9216) * 256 + tid;        // 65536
        int l = idx >> 6, h = idx & 63;
        PET[idx] = f2bf(PE[(h << 10) | l]);
    }
}

// PE-only transpose (fallback path)
__global__ void pe_only_kernel(const float* __restrict__ pe,
                               unsigned short* __restrict__ pet) {
    int idx = blockIdx.x * 256 + threadIdx.x;
    int l = idx >> 6, h = idx & 63;
    pet[idx] = f2bf(pe[(h << 10) | l]);
}

// ---------------- main kernel (v13): v12 with separate Wlds, ONE barrier/tile ----------------
// W in its own LDS buffer (wave-private) -> no K-alias WAR hazard -> barrier2
// deleted. LDS 40KB; grid 1024 caps residency at 4 blocks/CU anyway.
__global__ __launch_bounds__(256, 4) void attn_v13(
    const float* __restrict__ Qg, const unsigned short* __restrict__ Kws,
    const unsigned short* __restrict__ Vws, const unsigned short* __restrict__ PET,
    const float* __restrict__ SPAN, float* __restrict__ OUT)
{
    __shared__ unsigned short Klds[2][4096];      // 16 KB
    __shared__ unsigned short Vlds[2][4096];      // 16 KB
    __shared__ unsigned short Wlds[4][1024];      // 8 KB, per-wave, XOR-swizzled

    const int bid = blockIdx.x;
    const int b   = (bid & 7) * 16 + (bid >> 6);  // XCD swizzle (proven decode)
    const int i0  = ((bid >> 3) & 7) << 6;
    const int tid = threadIdx.x, w = tid >> 6, lane = tid & 63;
    const int c16 = lane & 15, g = lane >> 4;

    float z = SPAN[b & 15];
    z = fminf(fmaxf(z, 0.f), 1.f);
    const float mc = z * 32.f + 1.f - 1023.f * 0.03125f;   // msk = clamp(l/32 + mc, 0, 1)
    const int t_start = tstart_of(z);

    short8 qf0, qf1;      // Q pre-scaled by 0.125*log2e
    {
        const float* qp = Qg + ((size_t)((b << 9) + i0 + (w << 4) + c16) << 6) + (g << 3);
        qf0 = pack8s(*(const float4*)qp,        *(const float4*)(qp + 4),  QSCALE);
        qf1 = pack8s(*(const float4*)(qp + 32), *(const float4*)(qp + 36), QSCALE);
    }

    const f32x4 zero = {0.f, 0.f, 0.f, 0.f};
    f32x4 Oacc[4] = {zero, zero, zero, zero};
    f32x4 sumw = zero, sume = zero;
    f32x4 Sp[5];

    const char* kbase = (const char*)Kws + (((size_t)b * 1536 + i0) << 7);
    const char* vbase = (const char*)Vws + (((size_t)b * 24 + (i0 >> 6)) << 13);
    const int ubase = w << 10;                     // wave-uniform byte off in 8KB block
    const int loff  = ubase + lane * 16;

    // bpermute source addresses (loop-invariant per r)
    int bsrc[4];
#pragma unroll
    for (int r = 0; r < 4; ++r)
        bsrc[r] = ((lane & 48) | ((c16 - (g << 2) - r) & 15)) << 2;

#define STAGE(bufi, t) do {                                                    \
        const char* kg_ = kbase + (t) * 8192 + loff;                           \
        const char* vg_ = vbase + (t) * 8192 + loff;                           \
        unsigned short* kl_ = &Klds[bufi][ubase >> 1];                         \
        unsigned short* vl_ = &Vlds[bufi][ubase >> 1];                         \
        stage16(kg_, kl_); stage16(kg_ + 4096, kl_ + 2048);                    \
        stage16(vg_, vl_); stage16(vg_ + 4096, vl_ + 2048);                    \
    } while (0)

#define STRIP(dst, lbase) do {                                                 \
        int lr_ = (lbase) + c16;                                               \
        lr_ = lr_ < 0 ? 0 : (lr_ > 1023 ? 1023 : lr_);                         \
        const unsigned short* pp_ = PET + ((lr_ << 6) + (g << 3));             \
        short8 p0_ = *(const short8*)pp_;                                      \
        short8 p1_ = *(const short8*)(pp_ + 32);                               \
        f32x4 a_ = MFMA16(qf0, p0_, zero);                                     \
        dst = MFMA16(qf1, p1_, a_);                                            \
    } while (0)

    STAGE(t_start & 1, t_start);
    { const int lb0 = (t_start << 6) - (w << 4) - 16; STRIP(Sp[4], lb0); }

    for (int t = t_start; t < 17; ++t) {
        const int buf = t & 1;
        __syncthreads();                           // the ONLY barrier: stage(t) drained
        if (t < 16) STAGE(buf ^ 1, t + 1);         // prefetch overlaps whole tile body

        const int d0w = (t << 6) - (w << 4);
        const int lb  = d0w - 16;
        const bool edge = (t == 0) || (t == 16);

        // ---- content scores from Klds[buf] ----
        f32x4 Sc[4];
        const int xk = (c16 & 7) << 3;
#pragma unroll
        for (int jc = 0; jc < 4; ++jc) {
            const unsigned short* p = &Klds[buf][(jc * 16 + c16) << 6];
            short8 k0 = *(const short8*)(p + ((g << 3) ^ xk));
            short8 k1 = *(const short8*)(p + (((g << 3) + 32) ^ xk));
            f32x4 a = MFMA16(qf0, k0, zero);
            Sc[jc] = MFMA16(qf1, k1, a);
        }
        // ---- positional strips (rolling reuse) ----
        Sp[0] = Sp[4];
        STRIP(Sp[1], lb + 16);
        STRIP(Sp[2], lb + 32);
        STRIP(Sp[3], lb + 48);
        STRIP(Sp[4], lb + 64);

        // ---- combine + exp + span mask -> W (bf16, swizzled, wave-private Wlds) ----
        unsigned short* Wp = &Wlds[w][0];
#pragma unroll
        for (int r = 0; r < 4; ++r) {
            const int ii    = (g << 2) + r;
            const int delta = c16 - ii;
            const int sa    = bsrc[r];
            float sh0 = bpermf(sa, Sp[0][r]);
            float sh1 = bpermf(sa, Sp[1][r]);
            float sh2 = bpermf(sa, Sp[2][r]);
            float sh3 = bpermf(sa, Sp[3][r]);
            float sh4 = bpermf(sa, Sp[4][r]);
            const bool lo_ = delta < 0;
            const int xw = (ii & 7) << 3;
            const int lbase = d0w + delta;
            const float mb = fmaf((float)lbase, 0.03125f, mc);
#pragma unroll
            for (int jc = 0; jc < 4; ++jc) {
                float pa, pb;
                if (jc == 0) { pa = sh0; pb = sh1; }
                else if (jc == 1) { pa = sh1; pb = sh2; }
                else if (jc == 2) { pa = sh2; pb = sh3; }
                else { pa = sh3; pb = sh4; }
                const float pe = lo_ ? pa : pb;
                float e = EXP2F(Sc[jc][r] + pe);
                if (edge) {                        // wave-uniform branch
                    const int l_ = lbase + (jc << 4);
                    if ((unsigned)l_ >= 1024u) e = 0.f;
                }
                const float m_ = fminf(fmaxf(mb + 0.5f * jc, 0.f), 1.f);
                const float wgt = e * m_;
                sumw[r] += wgt;
                sume[r] += e;
                Wp[(ii << 6) + (((jc << 4) + c16) ^ xw)] = bfc(wgt);
            }
        }

        // ---- PV (W readback wave-local; compiler orders lgkm) ----
        const int xr = (c16 & 7) << 3;
        const unsigned short* wrow = Wp + (c16 << 6);
        short8 wf0 = *(const short8*)(wrow + ((g << 3) ^ xr));
        short8 wf1 = *(const short8*)(wrow + (((g << 3) + 32) ^ xr));
#pragma unroll
        for (int ht = 0; ht < 4; ++ht) {
            const unsigned short* vr = &Vlds[buf][(ht * 16 + c16) << 6];
            short8 v0 = *(const short8*)(vr + ((g << 3) ^ xr));
            short8 v1 = *(const short8*)(vr + (((g << 3) + 32) ^ xr));
            f32x4 a = MFMA16(wf0, v0, Oacc[ht]);
            Oacc[ht] = MFMA16(wf1, v1, a);
        }
    }

    // ---- epilogue ----
#pragma unroll
    for (int r = 0; r < 4; ++r) {
        float sw = sumw[r], se = sume[r];
#pragma unroll
        for (int m = 1; m < 16; m <<= 1) {
            sw += __shfl_xor(sw, m, 64);
            se += __shfl_xor(se, m, 64);
        }
        const float inv = 1.0f / (sw + 1e-8f * se);
        float* op = OUT + ((size_t)((b << 9) + i0 + (w << 4) + (g << 2) + r) << 6);
#pragma unroll
        for (int ht = 0; ht < 4; ++ht)
            op[ht * 16 + c16] = Oacc[ht][r] * inv;
    }
#undef STAGE
#undef STRIP
}

// ---------------- fallback v1 (ws too small for conversions) ----------------
__global__ __launch_bounds__(256, 4) void attn_v1(
    const float* __restrict__ Qg, const float* __restrict__ Kg,
    const float* __restrict__ Vg, const unsigned short* __restrict__ PET,
    const float* __restrict__ SPAN, float* __restrict__ OUT)
{
    __shared__ unsigned short Klds[64 * 72];
    __shared__ unsigned short Vlds[64 * 72];
    __shared__ unsigned short Wlds[4][16 * 72];

    const int bid = blockIdx.x;
    const int b  = (bid & 7) * 16 + (bid >> 6);
    const int qt = (bid >> 3) & 7;
    const int i0 = qt << 6;
    const int tid = threadIdx.x, w = tid >> 6, lane = tid & 63;
    const int c16 = lane & 15, g = lane >> 4;

    float z = SPAN[b & 15];
    z = fminf(fmaxf(z, 0.0f), 1.0f);
    const float zc = z * 32.0f + 1.0f;

    short8 qf0, qf1;
    {
        const float* qp = Qg + ((size_t)(b * 512 + i0 + w * 16 + c16) * 64 + g * 8);
        qf0 = pack8(*(const float4*)qp,        *(const float4*)(qp + 4));
        qf1 = pack8(*(const float4*)(qp + 32), *(const float4*)(qp + 36));
    }
    const f32x4 zero = {0.f, 0.f, 0.f, 0.f};
    f32x4 Oacc[4] = {zero, zero, zero, zero};
    f32x4 sumw = zero, sume = zero;
    const int d0w_off = -(w << 4);

    for (int dblk = 0; dblk < 17; ++dblk) {
        const int d = dblk << 6;
        __syncthreads();
        {
            const int row = tid >> 2, h0 = (tid & 3) << 4;
            const float* kp = Kg + ((size_t)(b * 1536 + i0 + d + row) * 64 + h0);
            float4 k0 = ((const float4*)kp)[0], k1 = ((const float4*)kp)[1];
            float4 k2 = ((const float4*)kp)[2], k3 = ((const float4*)kp)[3];
            *(short8*)&Klds[row * 72 + h0]     = pack8(k0, k1);
            *(short8*)&Klds[row * 72 + h0 + 8] = pack8(k2, k3);
        }
        {
            const int j0 = (tid & 31) << 1, h0 = (tid >> 5) << 3;
            const float* vp = Vg + ((size_t)(b * 1536 + i0 + d + j0) * 64 + h0);
            float4 a0 = ((const float4*)vp)[0], a1 = ((const float4*)vp)[1];
            float4 b0 = ((const float4*)(vp + 64))[0], b1 = ((const float4*)(vp + 64))[1];
            float ta[8] = {a0.x, a0.y, a0.z, a0.w, a1.x, a1.y, a1.z, a1.w};
            float tb[8] = {b0.x, b0.y, b0.z, b0.w, b1.x, b1.y, b1.z, b1.w};
#pragma unroll
            for (int u = 0; u < 8; ++u) {
                unsigned pv = (unsigned)f2bf(ta[u]) | ((unsigned)f2bf(tb[u]) << 16);
                *(unsigned*)&Vlds[(h0 + u) * 72 + j0] = pv;
            }
        }
        __syncthreads();

        const int d0w = d + d0w_off;
        const int lb  = d0w - 16;
        f32x4 Sp[5];
#pragma unroll
        for (int tt = 0; tt < 5; ++tt) {
            int lr = lb + (tt << 4) + c16;
            lr = lr < 0 ? 0 : (lr > 1023 ? 1023 : lr);
            const unsigned short* pp = PET + ((lr << 6) + (g << 3));
            short8 p0 = *(const short8*)pp;
            short8 p1 = *(const short8*)(pp + 32);
            f32x4 acc = MFMA16(qf0, p0, zero);
            Sp[tt] = MFMA16(qf1, p1, acc);
        }
        f32x4 Sc[4];
#pragma unroll
        for (int jc = 0; jc < 4; ++jc) {
            const unsigned short* kb = &Klds[(jc * 16 + c16) * 72 + (g << 3)];
            short8 k0 = *(const short8*)kb;
            short8 k1 = *(const short8*)(kb + 32);
            f32x4 acc = MFMA16(qf0, k0, zero);
            Sc[jc] = MFMA16(qf1, k1, acc);
        }
        unsigned short* Wp = Wlds[w];
#pragma unroll
        for (int jc = 0; jc < 4; ++jc) {
#pragma unroll
            for (int r = 0; r < 4; ++r) {
                const int ii    = (g << 2) + r;
                const int delta = c16 - ii;
                const int src   = (lane & 48) | (delta & 15);
                const float pa  = __shfl(Sp[jc][r],     src, 64);
                const float pb  = __shfl(Sp[jc + 1][r], src, 64);
                const float pe  = (delta >= 0) ? pb : pa;
                const int l     = d0w + (jc << 4) + delta;
                const float sv  = (Sc[jc][r] + pe) * 0.125f;
                const float e   = __expf(sv);
                const bool valid = ((unsigned)l < 1024u);
                float msk = (float)(l - 1023) * 0.03125f + zc;
                msk = fminf(fmaxf(msk, 0.0f), 1.0f);
                const float wgt = valid ? e * msk : 0.0f;
                sumw[r] += wgt;
                sume[r] += valid ? e : 0.0f;
                Wp[ii * 72 + (jc << 4) + c16] = f2bf(wgt);
            }
        }
        short8 wf0 = *(const short8*)&Wp[c16 * 72 + (g << 3)];
        short8 wf1 = *(const short8*)&Wp[c16 * 72 + 32 + (g << 3)];
#pragma unroll
        for (int ht = 0; ht < 4; ++ht) {
            const unsigned short* vb = &Vlds[(ht * 16 + c16) * 72 + (g << 3)];
            short8 v0 = *(const short8*)vb;
            short8 v1 = *(const short8*)(vb + 32);
            f32x4 a = MFMA16(wf0, v0, Oacc[ht]);
            Oacc[ht] = MFMA16(wf1, v1, a);
        }
    }
#pragma unroll
    for (int r = 0; r < 4; ++r) {
        float sw = sumw[r], se = sume[r];
#pragma unroll
        for (int m = 1; m < 16; m <<= 1) {
            sw += __shfl_xor(sw, m, 64);
            se += __shfl_xor(se, m, 64);
        }
        const float inv = 1.0f / (sw + 1e-8f * se);
        float* op = OUT + ((size_t)(b * 512 + i0 + w * 16 + (g << 2) + r) * 64);
#pragma unroll
        for (int ht = 0; ht < 4; ++ht)
            op[ht * 16 + c16] = Oacc[ht][r] * inv;
    }
}

extern "C" void kernel_launch(void* const* d_in, const int* in_sizes, int n_in,
                              void* d_out, int out_size, void* d_ws, size_t ws_size,
                              hipStream_t stream) {
    const float* Q    = (const float*)d_in[0];
    const float* K    = (const float*)d_in[1];
    const float* V    = (const float*)d_in[2];
    const float* PE   = (const float*)d_in[3];
    const float* SPAN = (const float*)d_in[4];

    const size_t VWS  = (size_t)128 * 24 * 4096 * 2;     // 25,165,824
    const size_t KWS  = (size_t)128 * 1536 * 64 * 2;     // 25,165,824
    const size_t PETB = (size_t)1024 * 64 * 2;           // 131,072
    const size_t NEED = VWS + KWS + PETB;

    if (ws_size >= NEED) {
        unsigned short* Vws = (unsigned short*)d_ws;
        unsigned short* Kws = (unsigned short*)((char*)d_ws + VWS);
        unsigned short* PET = (unsigned short*)((char*)d_ws + VWS + KWS);
        conv_all_kernel<<<9472, 256, 0, stream>>>(K, V, PE, SPAN, Kws, Vws, PET);
        attn_v13<<<1024, 256, 0, stream>>>(Q, Kws, Vws, PET, SPAN, (float*)d_out);
    } else {
        unsigned short* PET = (unsigned short*)d_ws;
        pe_only_kernel<<<256, 256, 0, stream>>>(PE, PET);
        attn_v1<<<1024, 256, 0, stream>>>(Q, K, V, PET, SPAN, (float*)d_out);
    }
}